// Round 4
// baseline (152.496 us; speedup 1.0000x reference)
//
#include <hip/hip_runtime.h>
#include <math.h>

#define NFM_B 16384
#define NFM_F 39
#define NFM_FP 40         // padded fields (slot 39: id=0, val=0)
#define NFM_E 16
#define NFM_H 200
#define TR    8           // rows per block (MFMA M=16 tile, rows 8..15 zero)
#define KPAD  232         // padded K row stride (shorts); 464B, 16B-aligned
#define NT    13          // n-tiles of 16 (208 >= 200)

typedef short short8  __attribute__((ext_vector_type(8)));   // 8 bf16 = 4 VGPRs
typedef short short4_t __attribute__((ext_vector_type(4)));
typedef float floatx4 __attribute__((ext_vector_type(4)));

__device__ __forceinline__ short f2bf(float x) {   // fp32 -> bf16 RNE
    union { float f; unsigned u; } a; a.f = x;
    unsigned r = a.u + 0x7FFF + ((a.u >> 16) & 1);
    return (short)(r >> 16);
}

// ws fragment layout (shorts):
//   frag idx ((tile*KS + ks)*64 + lane)*8 + j  holds  W[k][n] as bf16
//   with k = ks*32 + (lane>>4)*8 + j,  n = tile*16 + (lane&15), 0 if OOB.
#define W0F_OFF 0
#define W0F_SZ  (NT * 1 * 64 * 8)          // 6656
#define W1F_OFF (W0F_OFF + W0F_SZ)
#define W1F_SZ  (NT * 7 * 64 * 8)          // 46592
#define W2F_OFF (W1F_OFF + W1F_SZ)
#define W2F_SZ  (NT * 7 * 64 * 8)
#define WS_TOTAL (W2F_OFF + W2F_SZ)        // 99840 shorts = 199680 B

__global__ __launch_bounds__(256)
void nfm_prep_kernel(const float* __restrict__ w0,
                     const float* __restrict__ w1,
                     const float* __restrict__ w2,
                     short* __restrict__ ws)
{
    const int idx = blockIdx.x * 256 + threadIdx.x;
    if (idx >= WS_TOTAL) return;
    float val;
    if (idx < W1F_OFF) {
        const int rem = idx;
        const int j = rem & 7, lane = (rem >> 3) & 63, tile = rem >> 9;
        const int k = (lane >> 4) * 8 + j;
        const int n = tile * 16 + (lane & 15);
        val = (k < NFM_E && n < NFM_H) ? w0[k * NFM_H + n] : 0.f;
    } else if (idx < W2F_OFF) {
        const int rem = idx - W1F_OFF;
        const int j = rem & 7, lane = (rem >> 3) & 63;
        const int kt = rem >> 9;
        const int ks = kt % 7, tile = kt / 7;
        const int k = ks * 32 + (lane >> 4) * 8 + j;
        const int n = tile * 16 + (lane & 15);
        val = (k < NFM_H && n < NFM_H) ? w1[k * NFM_H + n] : 0.f;
    } else {
        const int rem = idx - W2F_OFF;
        const int j = rem & 7, lane = (rem >> 3) & 63;
        const int kt = rem >> 9;
        const int ks = kt % 7, tile = kt / 7;
        const int k = ks * 32 + (lane >> 4) * 8 + j;
        const int n = tile * 16 + (lane & 15);
        val = (k < NFM_H && n < NFM_H) ? w2[k * NFM_H + n] : 0.f;
    }
    ws[idx] = f2bf(val);
}

__global__ __launch_bounds__(256, 6)
void nfm_main_kernel(
    const int*   __restrict__ feat_ids,   // [B,F]
    const float* __restrict__ feat_vals,  // [B,F]
    const float* __restrict__ w,          // [VOCAB,1]
    const float* __restrict__ v,          // [VOCAB,E]
    const float* __restrict__ bglob,      // [1]
    const float* __restrict__ b0,
    const float* __restrict__ b1,
    const float* __restrict__ b2,
    const short* __restrict__ ws,         // bf16 weight fragments
    float* __restrict__ out)              // [B]
{
    __shared__ __attribute__((aligned(16))) short hbfA[16 * KPAD]; // 7424 B
    __shared__ __attribute__((aligned(16))) short hbfB[16 * KPAD];
    __shared__ int   idsS [TR * NFM_FP];
    __shared__ float valsS[TR * NFM_FP];
    __shared__ float rowsumW[4][16];
    __shared__ float lrS[TR];

    const int tid  = threadIdx.x;
    const int row0 = blockIdx.x * TR;
    const int lane = tid & 63;
    const int wv   = tid >> 6;     // wave 0..3
    const int lq   = lane >> 4;    // quad 0..3
    const int ln   = lane & 15;

    // Zero both activation buffers entirely (covers K-pad 200..231, dummy
    // rows 8..15, and fm pad cols 16..31). 928 short8 stores across block.
    {
        short8 z8 = {0, 0, 0, 0, 0, 0, 0, 0};
        short8* pA = (short8*)hbfA;
        short8* pB = (short8*)hbfB;
        for (int i = tid; i < 464; i += 256) { pA[i] = z8; pB[i] = z8; }
    }
    // Stage ids/vals, padded to 40 fields (slot 39 -> id 0, val 0)
    for (int i = tid; i < TR * NFM_FP; i += 256) {
        const int r = i / NFM_FP, f = i - r * NFM_FP;
        if (f < NFM_F) {
            idsS [i] = feat_ids [(row0 + r) * NFM_F + f];
            valsS[i] = feat_vals[(row0 + r) * NFM_F + f];
        } else {
            idsS[i] = 0; valsS[i] = 0.f;
        }
    }
    __syncthreads();

    // ---------- gather + FM pooling + LR: 32 lanes per row ----------
    // lane32 = fs*4 + eg: fs (0..7) strides fields, eg (0..3) picks the
    // float4 slice of the 64B embedding row -> 5 independent 16B loads.
    {
        const int r8  = tid >> 5;          // 0..7
        const int l32 = tid & 31;
        const int fs  = l32 >> 2, eg = l32 & 3;
        const int*   ids = idsS  + r8 * NFM_FP;
        const float* vls = valsS + r8 * NFM_FP;

        floatx4 xv = {0.f, 0.f, 0.f, 0.f}, x2 = {0.f, 0.f, 0.f, 0.f};
#pragma unroll
        for (int it = 0; it < 5; ++it) {
            const int f = fs + it * 8;     // max 39 = pad slot
            const float val = vls[f];
            const float4 ve = *(const float4*)&v[ids[f] * NFM_E + eg * 4];
            const float t0 = val * ve.x, t1 = val * ve.y;
            const float t2 = val * ve.z, t3 = val * ve.w;
            xv[0] += t0; xv[1] += t1; xv[2] += t2; xv[3] += t3;
            x2[0] = fmaf(t0, t0, x2[0]); x2[1] = fmaf(t1, t1, x2[1]);
            x2[2] = fmaf(t2, t2, x2[2]); x2[3] = fmaf(t3, t3, x2[3]);
        }
        // reduce over fs (xor offsets 4,8,16 within width 32)
#pragma unroll
        for (int off = 4; off <= 16; off <<= 1) {
#pragma unroll
            for (int c = 0; c < 4; ++c) {
                xv[c] += __shfl_xor(xv[c], off, 32);
                x2[c] += __shfl_xor(x2[c], off, 32);
            }
        }
        if (fs == 0) {
            short4_t fm4;
#pragma unroll
            for (int c = 0; c < 4; ++c)
                fm4[c] = f2bf(0.5f * (xv[c] * xv[c] - x2[c]));
            *(short4_t*)&hbfB[r8 * KPAD + eg * 4] = fm4;
        }
        // LR: lane covers field l32 and (padded) 32+l32
        float lr = vls[l32] * w[ids[l32]];
        if (l32 < 8) lr += vls[32 + l32] * w[ids[32 + l32]];
#pragma unroll
        for (int off = 16; off >= 1; off >>= 1)
            lr += __shfl_xor(lr, off, 32);
        if (l32 == 0) lrS[r8] = lr;
    }
    __syncthreads();

    // ---------- L0: fm(bf16, K=32) @ W0f -> hbfA ----------
    {
        const short8 af = *(const short8*)&hbfB[ln * KPAD + lq * 8];
        const short* Wf = ws + W0F_OFF;
        for (int t = wv; t < NT; t += 4) {
            const int n = t * 16 + ln;
            const float bj = (n < NFM_H) ? b0[n] : 0.f;
            floatx4 acc = {bj, bj, bj, bj};
            const short8 bf = *(const short8*)&Wf[(t * 64 + lane) * 8];
            acc = __builtin_amdgcn_mfma_f32_16x16x32_bf16(af, bf, acc, 0, 0, 0);
#pragma unroll
            for (int rg = 0; rg < 4; ++rg)          // n>=200 computes exact 0
                hbfA[(lq * 4 + rg) * KPAD + n] = f2bf(fmaxf(acc[rg], 0.f));
        }
    }
    __syncthreads();

    // ---------- L1: hbfA @ W1f -> hbfB ----------
    {
        short8 af[7];
#pragma unroll
        for (int ks = 0; ks < 7; ++ks)
            af[ks] = *(const short8*)&hbfA[ln * KPAD + ks * 32 + lq * 8];
        const short* Wf = ws + W1F_OFF;
        for (int t = wv; t < NT; t += 4) {
            const int n = t * 16 + ln;
            const float bj = (n < NFM_H) ? b1[n] : 0.f;
            floatx4 acc = {bj, bj, bj, bj};
#pragma unroll
            for (int ks = 0; ks < 7; ++ks) {
                const short8 bf = *(const short8*)&Wf[((t * 7 + ks) * 64 + lane) * 8];
                acc = __builtin_amdgcn_mfma_f32_16x16x32_bf16(af[ks], bf, acc, 0, 0, 0);
            }
#pragma unroll
            for (int rg = 0; rg < 4; ++rg)
                hbfB[(lq * 4 + rg) * KPAD + n] = f2bf(fmaxf(acc[rg], 0.f));
        }
    }
    __syncthreads();

    // ---------- L2: hbfB @ W2f -> row sums (no materialization) ----------
    {
        short8 af[7];
#pragma unroll
        for (int ks = 0; ks < 7; ++ks)
            af[ks] = *(const short8*)&hbfB[ln * KPAD + ks * 32 + lq * 8];
        const short* Wf = ws + W2F_OFF;
        float rs[4] = {0.f, 0.f, 0.f, 0.f};
        for (int t = wv; t < NT; t += 4) {
            const int n = t * 16 + ln;
            const float bj = (n < NFM_H) ? b2[n] : 0.f;
            floatx4 acc = {bj, bj, bj, bj};
#pragma unroll
            for (int ks = 0; ks < 7; ++ks) {
                const short8 bf = *(const short8*)&Wf[((t * 7 + ks) * 64 + lane) * 8];
                acc = __builtin_amdgcn_mfma_f32_16x16x32_bf16(af[ks], bf, acc, 0, 0, 0);
            }
#pragma unroll
            for (int rg = 0; rg < 4; ++rg)
                rs[rg] += fmaxf(acc[rg], 0.f);       // n>=200 adds exact 0
        }
#pragma unroll
        for (int off = 8; off >= 1; off >>= 1)
#pragma unroll
            for (int rg = 0; rg < 4; ++rg)
                rs[rg] += __shfl_xor(rs[rg], off, 16);
        if (ln == 0)
#pragma unroll
            for (int rg = 0; rg < 4; ++rg)
                rowsumW[wv][lq * 4 + rg] = rs[rg];
    }
    __syncthreads();

    // ---------- epilogue (rows 0..7 are real) ----------
    if (tid < TR) {
        const float s = rowsumW[0][tid] + rowsumW[1][tid]
                      + rowsumW[2][tid] + rowsumW[3][tid];
        const float logit = lrS[tid] + bglob[0] + s;
        out[row0 + tid] = 1.f / (1.f + expf(-logit));
    }
}

extern "C" void kernel_launch(void* const* d_in, const int* in_sizes, int n_in,
                              void* d_out, int out_size, void* d_ws, size_t ws_size,
                              hipStream_t stream) {
    const int*   feat_ids  = (const int*)  d_in[0];
    const float* feat_vals = (const float*)d_in[1];
    const float* w   = (const float*)d_in[2];
    const float* v   = (const float*)d_in[3];
    const float* b   = (const float*)d_in[4];
    const float* w0  = (const float*)d_in[5];
    const float* b0  = (const float*)d_in[6];
    const float* w1  = (const float*)d_in[7];
    const float* b1  = (const float*)d_in[8];
    const float* w2  = (const float*)d_in[9];
    const float* b2  = (const float*)d_in[10];
    float* out = (float*)d_out;
    short* ws  = (short*)d_ws;   // needs 199680 B

    hipLaunchKernelGGL(nfm_prep_kernel, dim3((WS_TOTAL + 255) / 256), dim3(256),
                       0, stream, w0, w1, w2, ws);
    hipLaunchKernelGGL(nfm_main_kernel, dim3(NFM_B / TR), dim3(256), 0, stream,
                       feat_ids, feat_vals, w, v, b, b0, b1, b2, ws, out);
}